// Round 1
// baseline (193.870 us; speedup 1.0000x reference)
//
#include <hip/hip_runtime.h>
#include <math.h>

// Problem constants (from reference setup_inputs)
#define BATCH   128
#define NCLS    200
#define KATTR   312
#define MH      28
#define MW      28
#define NMAPS   (BATCH * KATTR)        // 39936
#define MAP_ELEMS (MH * MW)            // 784
#define MAP_GROUPS (MAP_ELEMS / 4)     // 196 float4 per map
#define NREG    (BATCH * KATTR)        // 39936 elements in MSE

// Work partition
#define MAPS_PER_WAVE   8
#define WAVES_PER_BLOCK 4
#define MAPS_PER_BLOCK  (MAPS_PER_WAVE * WAVES_PER_BLOCK)   // 32
#define CPT_BLOCKS      (NMAPS / MAPS_PER_BLOCK)            // 1248 (exact)
#define CLS_BLOCKS      (BATCH / WAVES_PER_BLOCK)           // 32
#define REG_BLOCKS      8
#define TOTAL_BLOCKS    (CPT_BLOCKS + CLS_BLOCKS + REG_BLOCKS)

// ws layout (floats)
#define WS_CLS  0                       // 128 per-row CE values
#define WS_REG  (WS_CLS + BATCH)        // 8 MSE partials
#define WS_CPT  (WS_REG + REG_BLOCKS)   // 1248 cpt partials
#define WS_TOTAL (WS_CPT + CPT_BLOCKS)  // 1384 floats ~ 5.5 KB

#define COEF_CLS 1.0f
#define COEF_REG 1.0f
#define COEF_CPT 0.01f

__global__ __launch_bounds__(256) void apn_main(
    const float* __restrict__ class_scores,   // [128,200]
    const float* __restrict__ pred,           // [128,312]
    const float* __restrict__ gt,             // [128,312]
    const float* __restrict__ attn,           // [128,312,28,28]
    const int*   __restrict__ class_ids,      // [128]
    float* __restrict__ ws)
{
    const int tid  = threadIdx.x;
    const int lane = tid & 63;
    const int wave = tid >> 6;
    const int blk  = blockIdx.x;

    __shared__ float lds[WAVES_PER_BLOCK];

    if (blk < CPT_BLOCKS) {
        // ---- concentration loss: 1 wave per map, 8 maps per wave ----
        const int m0 = blk * MAPS_PER_BLOCK + wave * MAPS_PER_WAVE;
        float wsum = 0.0f;   // per-lane accumulator across all 8 maps

        for (int mm = 0; mm < MAPS_PER_WAVE; ++mm) {
            const float4* __restrict__ p4 =
                (const float4*)(attn + (size_t)(m0 + mm) * MAP_ELEMS);

            float4 v[4];
            float maxv = -INFINITY;
            int   maxi = 0;

            // load + in-lane argmax (scan in ascending flat index -> first-occurrence within lane)
            #pragma unroll
            for (int t = 0; t < 4; ++t) {
                const int g = lane + 64 * t;
                if (g < MAP_GROUPS) {
                    float4 x = p4[g];
                    v[t] = x;
                    const int bidx = g * 4;
                    if (x.x > maxv) { maxv = x.x; maxi = bidx;     }
                    if (x.y > maxv) { maxv = x.y; maxi = bidx + 1; }
                    if (x.z > maxv) { maxv = x.z; maxi = bidx + 2; }
                    if (x.w > maxv) { maxv = x.w; maxi = bidx + 3; }
                }
            }

            // wave argmax reduce (min flat index on ties == jnp.argmax semantics)
            #pragma unroll
            for (int off = 1; off < 64; off <<= 1) {
                float ov = __shfl_xor(maxv, off);
                int   oi = __shfl_xor(maxi, off);
                if (ov > maxv || (ov == maxv && oi < maxi)) { maxv = ov; maxi = oi; }
            }

            const float chf = (float)(maxi / MW);
            const float cwf = (float)(maxi % MW);

            // distance-weighted partial sum; accumulate per-lane (linear, reduce later)
            #pragma unroll
            for (int t = 0; t < 4; ++t) {
                const int g = lane + 64 * t;
                if (g < MAP_GROUPS) {
                    const int bidx = g * 4;
                    const float4 x = v[t];
                    {
                        int idx = bidx;     int h = idx / MW; int w = idx - h * MW;
                        float dh = (float)h - chf, dw = (float)w - cwf;
                        wsum += x.x * (dh * dh + dw * dw);
                    }
                    {
                        int idx = bidx + 1; int h = idx / MW; int w = idx - h * MW;
                        float dh = (float)h - chf, dw = (float)w - cwf;
                        wsum += x.y * (dh * dh + dw * dw);
                    }
                    {
                        int idx = bidx + 2; int h = idx / MW; int w = idx - h * MW;
                        float dh = (float)h - chf, dw = (float)w - cwf;
                        wsum += x.z * (dh * dh + dw * dw);
                    }
                    {
                        int idx = bidx + 3; int h = idx / MW; int w = idx - h * MW;
                        float dh = (float)h - chf, dw = (float)w - cwf;
                        wsum += x.w * (dh * dh + dw * dw);
                    }
                }
            }
        }

        // wave sum reduce
        #pragma unroll
        for (int off = 1; off < 64; off <<= 1) wsum += __shfl_xor(wsum, off);
        if (lane == 0) lds[wave] = wsum;
        __syncthreads();
        if (tid == 0) ws[WS_CPT + blk] = lds[0] + lds[1] + lds[2] + lds[3];

    } else if (blk < CPT_BLOCKS + CLS_BLOCKS) {
        // ---- cross-entropy: 1 wave per batch row ----
        const int row = (blk - CPT_BLOCKS) * WAVES_PER_BLOCK + wave;
        const float* __restrict__ xr = class_scores + (size_t)row * NCLS;

        float xv[4];
        float m = -INFINITY;
        #pragma unroll
        for (int t = 0; t < 4; ++t) {
            const int c = lane + 64 * t;
            if (c < NCLS) { xv[t] = xr[c]; m = fmaxf(m, xv[t]); }
            else            xv[t] = -INFINITY;
        }
        #pragma unroll
        for (int off = 1; off < 64; off <<= 1) m = fmaxf(m, __shfl_xor(m, off));

        float se = 0.0f;
        #pragma unroll
        for (int t = 0; t < 4; ++t) {
            const int c = lane + 64 * t;
            if (c < NCLS) se += expf(xv[t] - m);
        }
        #pragma unroll
        for (int off = 1; off < 64; off <<= 1) se += __shfl_xor(se, off);

        if (lane == 0) {
            const int cid = class_ids[row];
            const float lse = m + logf(se);
            ws[WS_CLS + row] = lse - xr[cid];
        }

    } else {
        // ---- MSE: float4 grid-stride over 9984 float4 groups ----
        const int rb = blk - CPT_BLOCKS - CLS_BLOCKS;   // 0..7
        const float4* __restrict__ p = (const float4*)pred;
        const float4* __restrict__ q = (const float4*)gt;
        float s = 0.0f;
        for (int i = rb * 256 + tid; i < NREG / 4; i += REG_BLOCKS * 256) {
            const float4 a = p[i];
            const float4 b = q[i];
            const float dx = a.x - b.x, dy = a.y - b.y, dz = a.z - b.z, dw = a.w - b.w;
            s += dx * dx + dy * dy + dz * dz + dw * dw;
        }
        #pragma unroll
        for (int off = 1; off < 64; off <<= 1) s += __shfl_xor(s, off);
        if (lane == 0) lds[wave] = s;
        __syncthreads();
        if (tid == 0) ws[WS_REG + rb] = lds[0] + lds[1] + lds[2] + lds[3];
    }
}

__global__ __launch_bounds__(256) void apn_final(
    const float* __restrict__ ws, float* __restrict__ out)
{
    const int tid  = threadIdx.x;
    const int lane = tid & 63;
    const int wave = tid >> 6;

    float a = 0.0f, b = 0.0f, c = 0.0f;
    for (int i = tid; i < BATCH; i += 256)      a += ws[WS_CLS + i];
    if (tid < REG_BLOCKS)                       b  = ws[WS_REG + tid];
    for (int i = tid; i < CPT_BLOCKS; i += 256) c += ws[WS_CPT + i];

    #pragma unroll
    for (int off = 1; off < 64; off <<= 1) {
        a += __shfl_xor(a, off);
        b += __shfl_xor(b, off);
        c += __shfl_xor(c, off);
    }

    __shared__ float la[4], lb[4], lc[4];
    if (lane == 0) { la[wave] = a; lb[wave] = b; lc[wave] = c; }
    __syncthreads();
    if (tid == 0) {
        const float sa = la[0] + la[1] + la[2] + la[3];
        const float sb = lb[0] + lb[1] + lb[2] + lb[3];
        const float sc = lc[0] + lc[1] + lc[2] + lc[3];
        const float l_cls = COEF_CLS * (sa / (float)BATCH);
        const float l_reg = COEF_REG * (sb / (float)NREG);
        const float l_cpt = COEF_CPT * (sc / ((float)NMAPS * (float)MAP_ELEMS));
        out[0] = l_cls;
        out[1] = l_reg;
        out[2] = l_cpt;
        out[3] = l_cls + l_reg + l_cpt;
    }
}

extern "C" void kernel_launch(void* const* d_in, const int* in_sizes, int n_in,
                              void* d_out, int out_size, void* d_ws, size_t ws_size,
                              hipStream_t stream) {
    const float* class_scores = (const float*)d_in[0];
    const float* pred         = (const float*)d_in[1];
    const float* gt           = (const float*)d_in[2];
    const float* attn         = (const float*)d_in[3];
    const int*   class_ids    = (const int*)d_in[4];
    float* ws  = (float*)d_ws;
    float* out = (float*)d_out;

    apn_main<<<dim3(TOTAL_BLOCKS), dim3(256), 0, stream>>>(
        class_scores, pred, gt, attn, class_ids, ws);
    apn_final<<<dim3(1), dim3(256), 0, stream>>>(ws, out);
}